// Round 4
// baseline (1575.883 us; speedup 1.0000x reference)
//
#include <hip/hip_runtime.h>

#define KD 12288   // rows/cols of adj
#define FIN 500
#define KPAD 512
#define HID 64
#define NOUT 16

typedef __attribute__((ext_vector_type(8))) short bf16x8;
typedef __attribute__((ext_vector_type(4))) float f32x4;

__device__ __forceinline__ unsigned short f2bf(float f) {
  union { float f; unsigned int u; } v; v.f = f;
  unsigned int u = v.u;
  unsigned int r = (u + 0x7fffu + ((u >> 16) & 1u)) >> 16;  // RTN-even
  return (unsigned short)r;
}

__device__ __forceinline__ unsigned long long pack4(float4 v) {
  unsigned int lo = (unsigned int)f2bf(v.x) | ((unsigned int)f2bf(v.y) << 16);
  unsigned int hi = (unsigned int)f2bf(v.z) | ((unsigned int)f2bf(v.w) << 16);
  return (unsigned long long)lo | ((unsigned long long)hi << 32);
}

__device__ __forceinline__ bf16x8 cvt8(float4 lo, float4 hi) {
  union { unsigned long long u[2]; bf16x8 v; } r;
  r.u[0] = pack4(lo); r.u[1] = pack4(hi);
  return r.v;
}

__device__ __forceinline__ f32x4 mfma16(bf16x8 a, bf16x8 b, f32x4 c) {
  return __builtin_amdgcn_mfma_f32_16x16x32_bf16(a, b, c, 0, 0, 0);
}

// A-tile fragment-ordered LDS layout (used by k_g1/k_g2 only).
__device__ __forceinline__ int a_slot(int hg, int r, int ibyte) {
  return (((hg << 4) + r) << 4 | ibyte) ^ ((hg & 7) << 4);
}

// ---------------- setup: W1 -> W1T bf16 [64][512] (zero-padded), W2 -> W2T bf16 [16][64]
__global__ void k_setup(const float* __restrict__ W1, const float* __restrict__ W2,
                        unsigned short* __restrict__ W1T, unsigned short* __restrict__ W2T) {
  int flat = blockIdx.x * 256 + threadIdx.x;
  if (flat < HID * KPAD) {
    int c = flat >> 9, k = flat & (KPAD - 1);
    W1T[flat] = (k < FIN) ? f2bf(W1[k * HID + c]) : (unsigned short)0;
  } else {
    int f2 = flat - HID * KPAD;
    if (f2 < NOUT * HID) {
      int c = f2 >> 6, k = f2 & 63;
      W2T[f2] = f2bf(W2[k * NOUT + c]);
    }
  }
}

// ---------------- GEMM1: h1T[c][r] = (x @ W1 + b1)^T  (bf16 out)
__global__ __launch_bounds__(256) void k_g1(const float* __restrict__ x,
                                            const unsigned short* __restrict__ W1T,
                                            const float* __restrict__ b1,
                                            unsigned short* __restrict__ h1T) {
  __shared__ unsigned char Ab[2][2048];
  __shared__ unsigned short tr[64][16];
  const int tid = threadIdx.x;
  const int w = tid >> 6, l = tid & 63;
  const int r0 = blockIdx.x << 4;
  const int sr = tid >> 4, sk4 = (tid & 15) << 2;
  const int shg = sk4 >> 3;
  const int aw = a_slot(shg, sr, (sk4 & 7) << 1);
  const int fr = l & 15, fg = l >> 4;
  const int ar0 = a_slot(fg, fr, 0);
  const int ar1 = a_slot(4 + fg, fr, 0);
  const float* ap = x + (size_t)(r0 + sr) * FIN;
  const unsigned short* bp = W1T + (w * 16 + fr) * KPAD + (fg << 3);
  f32x4 acc = {0.f, 0.f, 0.f, 0.f};
  for (int s = 0; s < KPAD / 64; ++s) {
    int k0 = s * 64 + sk4;
    float4 av = make_float4(0.f, 0.f, 0.f, 0.f);
    if (k0 < FIN) av = *(const float4*)(ap + k0);
    unsigned char* buf = Ab[s & 1];
    *(unsigned long long*)(buf + aw) = pack4(av);
    __syncthreads();
    bf16x8 a0 = *(const bf16x8*)(buf + ar0);
    bf16x8 a1 = *(const bf16x8*)(buf + ar1);
    bf16x8 b0 = *(const bf16x8*)(bp + s * 64);
    bf16x8 b1v = *(const bf16x8*)(bp + s * 64 + 32);
    acc = mfma16(a0, b0, acc);
    acc = mfma16(a1, b1v, acc);
    __syncthreads();
  }
  const int c = w * 16 + fr;
  const float bias = b1[c];
#pragma unroll
  for (int q = 0; q < 4; ++q) tr[c][fg * 4 + q] = f2bf(acc[q] + bias);
  __syncthreads();
  int cc = tid >> 2, rr = (tid & 3) << 2;
  *(unsigned long long*)(h1T + (size_t)cc * KD + r0 + rr) = *(unsigned long long*)&tr[cc][rr];
}

// ---------------- L1: H[r][c] = relu(adj @ h1)  — LDS-free, barrier-free, 2-slot ring
__global__ __launch_bounds__(256) void k_l1(const float* __restrict__ adj,
                                            const unsigned short* __restrict__ h1T,
                                            unsigned short* __restrict__ H) {
  const int tid = threadIdx.x;
  const int w = tid >> 6, l = tid & 63;
  const int r0 = blockIdx.x << 4;
  const int fr = l & 15, fg = l >> 4;
  // lane base: row (r0+fr), k offset fg*8  (A direct from global, fp32)
  const float* ap = adj + (size_t)(r0 + fr) * KD + (fg << 3);
  const unsigned short* bp = h1T + (size_t)(w * 16 + fr) * KD + (fg << 3);
  f32x4 acc = {0.f, 0.f, 0.f, 0.f};
  const int NS = KD / 64;  // 192, even
  // ring slot A (even steps), slot B (odd steps) — all statically named regs
  float4 aA0, aA1, aA2, aA3, aB0, aB1, aB2, aB3;
  bf16x8 bA0, bA1, bB0, bB1;
  {
    const float* p = ap;                         // s = 0
    aA0 = *(const float4*)(p);      aA1 = *(const float4*)(p + 4);
    aA2 = *(const float4*)(p + 32); aA3 = *(const float4*)(p + 36);
    const unsigned short* q = bp;
    bA0 = *(const bf16x8*)(q);      bA1 = *(const bf16x8*)(q + 32);
    p = ap + 64;                                 // s = 1
    aB0 = *(const float4*)(p);      aB1 = *(const float4*)(p + 4);
    aB2 = *(const float4*)(p + 32); aB3 = *(const float4*)(p + 36);
    q = bp + 64;
    bB0 = *(const bf16x8*)(q);      bB1 = *(const bf16x8*)(q + 32);
  }
  for (int s = 0; s < NS; s += 2) {
    // consume slot A (step s)
    acc = mfma16(cvt8(aA0, aA1), bA0, acc);
    acc = mfma16(cvt8(aA2, aA3), bA1, acc);
    // issue step s+2 into slot A (dummy re-read of s at tail — harmless)
    {
      int sn = (s + 2 < NS) ? s + 2 : s;
      const float* p = ap + (size_t)sn * 64;
      aA0 = *(const float4*)(p);      aA1 = *(const float4*)(p + 4);
      aA2 = *(const float4*)(p + 32); aA3 = *(const float4*)(p + 36);
      const unsigned short* q = bp + (size_t)sn * 64;
      bA0 = *(const bf16x8*)(q);      bA1 = *(const bf16x8*)(q + 32);
    }
    // consume slot B (step s+1)
    acc = mfma16(cvt8(aB0, aB1), bB0, acc);
    acc = mfma16(cvt8(aB2, aB3), bB1, acc);
    // issue step s+3 into slot B
    {
      int sn = (s + 3 < NS) ? s + 3 : s + 1;
      const float* p = ap + (size_t)sn * 64;
      aB0 = *(const float4*)(p);      aB1 = *(const float4*)(p + 4);
      aB2 = *(const float4*)(p + 32); aB3 = *(const float4*)(p + 36);
      const unsigned short* q = bp + (size_t)sn * 64;
      bB0 = *(const bf16x8*)(q);      bB1 = *(const bf16x8*)(q + 32);
    }
  }
  const int c = w * 16 + fr;
#pragma unroll
  for (int q = 0; q < 4; ++q) {
    float v = acc[q];
    v = v > 0.f ? v : 0.f;
    H[(size_t)(r0 + fg * 4 + q) * HID + c] = f2bf(v);
  }
}

// ---------------- GEMM2: h2T[c][r] = (H @ W2 + b2)^T  (bf16 out), 1 wave / 16 rows
__global__ __launch_bounds__(64) void k_g2(const unsigned short* __restrict__ Hm,
                                           const unsigned short* __restrict__ W2T,
                                           const float* __restrict__ b2,
                                           unsigned short* __restrict__ h2T) {
  __shared__ unsigned char Ab[2048];
  __shared__ unsigned short tr[16][16];
  const int l = threadIdx.x;
  const int r0 = blockIdx.x << 4;
  const int fr = l & 15, fg = l >> 4;
  const int sr = l >> 2;
#pragma unroll
  for (int j = 0; j < 4; ++j) {
    int k4 = (l & 3) * 16 + j * 4;
    int hg = k4 >> 3;
    unsigned long long v = *(const unsigned long long*)(Hm + (size_t)(r0 + sr) * HID + k4);
    *(unsigned long long*)(Ab + a_slot(hg, sr, (k4 & 7) << 1)) = v;
  }
  __syncthreads();
  bf16x8 a0 = *(const bf16x8*)(Ab + a_slot(fg, fr, 0));
  bf16x8 a1 = *(const bf16x8*)(Ab + a_slot(4 + fg, fr, 0));
  bf16x8 b0 = *(const bf16x8*)(W2T + fr * HID + fg * 8);
  bf16x8 b1v = *(const bf16x8*)(W2T + fr * HID + 32 + fg * 8);
  f32x4 acc = {0.f, 0.f, 0.f, 0.f};
  acc = mfma16(a0, b0, acc);
  acc = mfma16(a1, b1v, acc);
  const float bias = b2[fr];
#pragma unroll
  for (int q = 0; q < 4; ++q) tr[fr][fg * 4 + q] = f2bf(acc[q] + bias);
  __syncthreads();
  int cc = l >> 2, rr = (l & 3) << 2;
  *(unsigned long long*)(h2T + (size_t)cc * KD + r0 + rr) = *(unsigned long long*)&tr[cc][rr];
}

// ---------------- L2: out = adj @ h2 — LDS-free main loop, K split across 4 waves
__global__ __launch_bounds__(256) void k_l2(const float* __restrict__ adj,
                                            const unsigned short* __restrict__ h2T,
                                            float* __restrict__ out) {
  __shared__ float red[4][16][16];
  const int tid = threadIdx.x;
  const int w = tid >> 6, l = tid & 63;
  const int r0 = blockIdx.x << 4;
  const int kb = w * (KD / 4);
  const int fr = l & 15, fg = l >> 4;
  const float* ap = adj + (size_t)(r0 + fr) * KD + kb + (fg << 3);
  const unsigned short* bp = h2T + (size_t)fr * KD + kb + (fg << 3);
  f32x4 acc = {0.f, 0.f, 0.f, 0.f};
  const int NS = (KD / 4) / 64;  // 48, even
  float4 aA0, aA1, aA2, aA3, aB0, aB1, aB2, aB3;
  bf16x8 bA0, bA1, bB0, bB1;
  {
    const float* p = ap;
    aA0 = *(const float4*)(p);      aA1 = *(const float4*)(p + 4);
    aA2 = *(const float4*)(p + 32); aA3 = *(const float4*)(p + 36);
    const unsigned short* q = bp;
    bA0 = *(const bf16x8*)(q);      bA1 = *(const bf16x8*)(q + 32);
    p = ap + 64;
    aB0 = *(const float4*)(p);      aB1 = *(const float4*)(p + 4);
    aB2 = *(const float4*)(p + 32); aB3 = *(const float4*)(p + 36);
    q = bp + 64;
    bB0 = *(const bf16x8*)(q);      bB1 = *(const bf16x8*)(q + 32);
  }
  for (int s = 0; s < NS; s += 2) {
    acc = mfma16(cvt8(aA0, aA1), bA0, acc);
    acc = mfma16(cvt8(aA2, aA3), bA1, acc);
    {
      int sn = (s + 2 < NS) ? s + 2 : s;
      const float* p = ap + (size_t)sn * 64;
      aA0 = *(const float4*)(p);      aA1 = *(const float4*)(p + 4);
      aA2 = *(const float4*)(p + 32); aA3 = *(const float4*)(p + 36);
      const unsigned short* q = bp + (size_t)sn * 64;
      bA0 = *(const bf16x8*)(q);      bA1 = *(const bf16x8*)(q + 32);
    }
    acc = mfma16(cvt8(aB0, aB1), bB0, acc);
    acc = mfma16(cvt8(aB2, aB3), bB1, acc);
    {
      int sn = (s + 3 < NS) ? s + 3 : s + 1;
      const float* p = ap + (size_t)sn * 64;
      aB0 = *(const float4*)(p);      aB1 = *(const float4*)(p + 4);
      aB2 = *(const float4*)(p + 32); aB3 = *(const float4*)(p + 36);
      const unsigned short* q = bp + (size_t)sn * 64;
      bB0 = *(const bf16x8*)(q);      bB1 = *(const bf16x8*)(q + 32);
    }
  }
#pragma unroll
  for (int q = 0; q < 4; ++q) red[w][fg * 4 + q][fr] = acc[q];
  __syncthreads();
  int rr = tid >> 4, cc = tid & 15;
  float sum = red[0][rr][cc] + red[1][rr][cc] + red[2][rr][cc] + red[3][rr][cc];
  out[(size_t)(r0 + rr) * NOUT + cc] = sum;
}

extern "C" void kernel_launch(void* const* d_in, const int* in_sizes, int n_in,
                              void* d_out, int out_size, void* d_ws, size_t ws_size,
                              hipStream_t stream) {
  const float* x   = (const float*)d_in[0];
  const float* adj = (const float*)d_in[1];
  const float* W1  = (const float*)d_in[2];
  const float* b1  = (const float*)d_in[3];
  const float* W2  = (const float*)d_in[4];
  const float* b2  = (const float*)d_in[5];
  float* out = (float*)d_out;
  char* ws = (char*)d_ws;
  // ws layout (bytes): W1T 65536 | W2T 2048 | h1T 1572864 | H 1572864 | h2T 393216
  unsigned short* W1T = (unsigned short*)(ws);
  unsigned short* W2T = (unsigned short*)(ws + 65536);
  unsigned short* h1T = (unsigned short*)(ws + 67584);
  unsigned short* Hm  = (unsigned short*)(ws + 1640448);
  unsigned short* h2T = (unsigned short*)(ws + 3213312);

  hipLaunchKernelGGL(k_setup, dim3(132), dim3(256), 0, stream, W1, W2, W1T, W2T);
  hipLaunchKernelGGL(k_g1, dim3(KD / 16), dim3(256), 0, stream, x, W1T, b1, h1T);
  hipLaunchKernelGGL(k_l1, dim3(KD / 16), dim3(256), 0, stream, adj, h1T, Hm);
  hipLaunchKernelGGL(k_g2, dim3(KD / 16), dim3(64), 0, stream, Hm, W2T, b2, h2T);
  hipLaunchKernelGGL(k_l2, dim3(KD / 16), dim3(256), 0, stream, adj, h2T, out);
}

// Round 6
// 967.848 us; speedup vs baseline: 1.6282x; 1.6282x over previous
//
#include <hip/hip_runtime.h>

#define KD 12288   // rows/cols of adj
#define FIN 500
#define KPAD 512
#define HID 64
#define NOUT 16

typedef __attribute__((ext_vector_type(8))) short bf16x8;
typedef __attribute__((ext_vector_type(4))) float f32x4;

typedef __attribute__((address_space(1))) const unsigned int GU;
typedef __attribute__((address_space(3))) unsigned int LU;

__device__ __forceinline__ void gload16(const void* g, void* l) {
  __builtin_amdgcn_global_load_lds((GU*)g, (LU*)l, 16, 0, 0);
}
#define WAITV(N) asm volatile("s_waitcnt vmcnt(" #N ")" ::: "memory")
#define BAR() do { __builtin_amdgcn_s_barrier(); __builtin_amdgcn_sched_barrier(0); } while (0)

__device__ __forceinline__ unsigned short f2bf(float f) {
  union { float f; unsigned int u; } v; v.f = f;
  unsigned int u = v.u;
  unsigned int r = (u + 0x7fffu + ((u >> 16) & 1u)) >> 16;  // RTN-even
  return (unsigned short)r;
}

__device__ __forceinline__ unsigned long long pack4(float4 v) {
  unsigned int lo = (unsigned int)f2bf(v.x) | ((unsigned int)f2bf(v.y) << 16);
  unsigned int hi = (unsigned int)f2bf(v.z) | ((unsigned int)f2bf(v.w) << 16);
  return (unsigned long long)lo | ((unsigned long long)hi << 32);
}

__device__ __forceinline__ bf16x8 cvt8(float4 lo, float4 hi) {
  union { unsigned long long u[2]; bf16x8 v; } r;
  r.u[0] = pack4(lo); r.u[1] = pack4(hi);
  return r.v;
}

__device__ __forceinline__ f32x4 mfma16(bf16x8 a, bf16x8 b, f32x4 c) {
  return __builtin_amdgcn_mfma_f32_16x16x32_bf16(a, b, c, 0, 0, 0);
}

// fragment-ordered LDS layout helper (k_g1/k_g2 only)
__device__ __forceinline__ int a_slot(int hg, int r, int ibyte) {
  return (((hg << 4) + r) << 4 | ibyte) ^ ((hg & 7) << 4);
}

// ---------------- setup: W1T bf16 [64][512] (pad), W2T bf16 [16][64], zero out
__global__ void k_setup(const float* __restrict__ W1, const float* __restrict__ W2,
                        unsigned short* __restrict__ W1T, unsigned short* __restrict__ W2T,
                        float* __restrict__ out) {
  int flat = blockIdx.x * 256 + threadIdx.x;
  if (flat < HID * KPAD) {
    int c = flat >> 9, k = flat & (KPAD - 1);
    W1T[flat] = (k < FIN) ? f2bf(W1[k * HID + c]) : (unsigned short)0;
  } else if (flat < HID * KPAD + NOUT * HID) {
    int f2 = flat - HID * KPAD;
    int c = f2 >> 6, k = f2 & 63;
    W2T[f2] = f2bf(W2[k * NOUT + c]);
  } else {
    int f3 = flat - (HID * KPAD + NOUT * HID);
    if (f3 < KD * NOUT) out[f3] = 0.f;
  }
}

// ---------------- GEMM1: h1T[c][r] = (x @ W1 + b1)^T  (bf16 out)
__global__ __launch_bounds__(256) void k_g1(const float* __restrict__ x,
                                            const unsigned short* __restrict__ W1T,
                                            const float* __restrict__ b1,
                                            unsigned short* __restrict__ h1T) {
  __shared__ unsigned char Ab[2][2048];
  __shared__ unsigned short tr[64][16];
  const int tid = threadIdx.x;
  const int w = tid >> 6, l = tid & 63;
  const int r0 = blockIdx.x << 4;
  const int sr = tid >> 4, sk4 = (tid & 15) << 2;
  const int shg = sk4 >> 3;
  const int aw = a_slot(shg, sr, (sk4 & 7) << 1);
  const int fr = l & 15, fg = l >> 4;
  const int ar0 = a_slot(fg, fr, 0);
  const int ar1 = a_slot(4 + fg, fr, 0);
  const float* ap = x + (size_t)(r0 + sr) * FIN;
  const unsigned short* bp = W1T + (w * 16 + fr) * KPAD + (fg << 3);
  f32x4 acc = {0.f, 0.f, 0.f, 0.f};
  for (int s = 0; s < KPAD / 64; ++s) {
    int k0 = s * 64 + sk4;
    float4 av = make_float4(0.f, 0.f, 0.f, 0.f);
    if (k0 < FIN) av = *(const float4*)(ap + k0);
    unsigned char* buf = Ab[s & 1];
    *(unsigned long long*)(buf + aw) = pack4(av);
    __syncthreads();
    bf16x8 a0 = *(const bf16x8*)(buf + ar0);
    bf16x8 a1 = *(const bf16x8*)(buf + ar1);
    bf16x8 b0 = *(const bf16x8*)(bp + s * 64);
    bf16x8 b1v = *(const bf16x8*)(bp + s * 64 + 32);
    acc = mfma16(a0, b0, acc);
    acc = mfma16(a1, b1v, acc);
    __syncthreads();
  }
  const int c = w * 16 + fr;
  const float bias = b1[c];
#pragma unroll
  for (int q = 0; q < 4; ++q) tr[c][fg * 4 + q] = f2bf(acc[q] + bias);
  __syncthreads();
  int cc = tid >> 2, rr = (tid & 3) << 2;
  *(unsigned long long*)(h1T + (size_t)cc * KD + r0 + rr) = *(unsigned long long*)&tr[cc][rr];
}

// ---------------- L1: H = relu(adj @ h1). 16 rows x 64 cols per block.
// D=4 LDS ring, global_load_lds staging, counted vmcnt(6), 1 barrier/step.
__global__ __launch_bounds__(256) void k_l1(const float* __restrict__ adj,
                                            const unsigned short* __restrict__ h1T,
                                            unsigned short* __restrict__ H) {
  __shared__ __align__(1024) unsigned char As[4][4096];   // 16r x 64k fp32
  __shared__ __align__(1024) unsigned char Bs[4][8192];   // 64c x 64k bf16
  const int tid = threadIdx.x;
  const int w = tid >> 6, l = tid & 63;
  const int r0 = blockIdx.x << 4;
  const int fr = l & 15, fg = l >> 4;
  // A staging: slot=tid -> row sr, 16B chunk (sc ^ (sr&7)) of the row's 64 k
  const int sr = tid >> 4;
  const int sc = (tid & 15) ^ (sr & 7);
  const float* aRun = adj + (size_t)(r0 + sr) * KD + (sc << 2);
  // B staging: slot=tid -> col bc, 8k-group bh (swizzled); slot tid+256 = +32 cols
  const int bc = tid >> 3;
  const int bh = (tid & 7) ^ (bc & 7);
  const unsigned short* bRun = h1T + (size_t)bc * KD + (bh << 3);
  const unsigned char* aW = (const unsigned char*)&As[0][0] + (w << 10);  // wave-uniform
  const unsigned char* bW = (const unsigned char*)&Bs[0][0] + (w << 10);
  // frag lane offsets (buffer 0): A row fr, 16B slots (j ^ (fr&7)), j=2fg,2fg+1 (+8 for hi)
  const int x7 = fr & 7;
  const int aOff0 = fr * 256 + ((((fg << 1) | 0) ^ x7) << 4);
  const int aOff1 = fr * 256 + ((((fg << 1) | 1) ^ x7) << 4);
  const int aOff2 = fr * 256 + (((8 + (fg << 1)) ^ x7) << 4);
  const int aOff3 = fr * 256 + (((9 + (fg << 1)) ^ x7) << 4);
  const int cB = w * 16 + fr;
  const int bOff0 = cB * 128 + ((fg ^ (cB & 7)) << 4);
  const int bOff1 = cB * 128 + (((4 + fg) ^ (cB & 7)) << 4);
  f32x4 acc = {0.f, 0.f, 0.f, 0.f};
  const int NS = KD / 64;  // 192
  // prologue: stage steps 0..2  (3 vmem/wave per step)
#pragma unroll
  for (int d = 0; d < 3; ++d) {
    gload16(aRun, (void*)(aW + d * 4096));
    gload16(bRun, (void*)(bW + d * 8192));
    gload16(bRun + (size_t)32 * KD, (void*)(bW + d * 8192 + 4096));
    aRun += 64; bRun += 64;
  }
#define L1_COMPUTE(S)                                                          \
  {                                                                            \
    const unsigned char* ab = (const unsigned char*)&As[(S) & 3][0];           \
    const unsigned char* bb = (const unsigned char*)&Bs[(S) & 3][0];           \
    bf16x8 a0 = cvt8(*(const float4*)(ab + aOff0), *(const float4*)(ab + aOff1)); \
    bf16x8 a1 = cvt8(*(const float4*)(ab + aOff2), *(const float4*)(ab + aOff3)); \
    bf16x8 b0 = *(const bf16x8*)(bb + bOff0);                                  \
    bf16x8 b1 = *(const bf16x8*)(bb + bOff1);                                  \
    acc = mfma16(a0, b0, acc);                                                 \
    acc = mfma16(a1, b1, acc);                                                 \
  }
  for (int s = 0; s < NS - 3; ++s) {
    WAITV(6);   // stage(s) complete (own wave); barrier makes it block-wide
    BAR();
    int d = (s + 3) & 3;
    gload16(aRun, (void*)(aW + d * 4096));
    gload16(bRun, (void*)(bW + d * 8192));
    gload16(bRun + (size_t)32 * KD, (void*)(bW + d * 8192 + 4096));
    aRun += 64; bRun += 64;
    L1_COMPUTE(s);
  }
  WAITV(6); BAR(); L1_COMPUTE(NS - 3);
  WAITV(3); BAR(); L1_COMPUTE(NS - 2);
  WAITV(0); BAR(); L1_COMPUTE(NS - 1);
  const int c = w * 16 + fr;
#pragma unroll
  for (int q = 0; q < 4; ++q) {
    float v = acc[q];
    v = v > 0.f ? v : 0.f;
    H[(size_t)(r0 + fg * 4 + q) * HID + c] = f2bf(v);
  }
}

// ---------------- GEMM2: h2T[c][r] = (H @ W2 + b2)^T  (bf16 out)
__global__ __launch_bounds__(64) void k_g2(const unsigned short* __restrict__ Hm,
                                           const unsigned short* __restrict__ W2T,
                                           const float* __restrict__ b2,
                                           unsigned short* __restrict__ h2T) {
  __shared__ unsigned char Ab[2048];
  __shared__ unsigned short tr[16][16];
  const int l = threadIdx.x;
  const int r0 = blockIdx.x << 4;
  const int fr = l & 15, fg = l >> 4;
  const int sr = l >> 2;
#pragma unroll
  for (int j = 0; j < 4; ++j) {
    int k4 = (l & 3) * 16 + j * 4;
    int hg = k4 >> 3;
    unsigned long long v = *(const unsigned long long*)(Hm + (size_t)(r0 + sr) * HID + k4);
    *(unsigned long long*)(Ab + a_slot(hg, sr, (k4 & 7) << 1)) = v;
  }
  __syncthreads();
  bf16x8 a0 = *(const bf16x8*)(Ab + a_slot(fg, fr, 0));
  bf16x8 a1 = *(const bf16x8*)(Ab + a_slot(4 + fg, fr, 0));
  bf16x8 b0 = *(const bf16x8*)(W2T + fr * HID + fg * 8);
  bf16x8 b1v = *(const bf16x8*)(W2T + fr * HID + 32 + fg * 8);
  f32x4 acc = {0.f, 0.f, 0.f, 0.f};
  acc = mfma16(a0, b0, acc);
  acc = mfma16(a1, b1v, acc);
  const float bias = b2[fr];
#pragma unroll
  for (int q = 0; q < 4; ++q) tr[fr][fg * 4 + q] = f2bf(acc[q] + bias);
  __syncthreads();
  int cc = l >> 2, rr = (l & 3) << 2;
  *(unsigned long long*)(h2T + (size_t)cc * KD + r0 + rr) = *(unsigned long long*)&tr[cc][rr];
}

// ---------------- L2: out += adj @ h2. 64 rows x 16 cols per block, K/4 per block.
// Same D=4 ring / vmcnt(6) template; 32-k steps; atomicAdd partials.
__global__ __launch_bounds__(256) void k_l2(const float* __restrict__ adj,
                                            const unsigned short* __restrict__ h2T,
                                            float* __restrict__ out) {
  __shared__ __align__(1024) unsigned char As[4][8192];   // 64r x 32k fp32
  __shared__ __align__(1024) unsigned char Bs[4][1024];   // 16c x 32k bf16
  const int tid = threadIdx.x;
  const int w = tid >> 6, l = tid & 63;
  const int bt = blockIdx.x;
  const int r0 = (bt >> 2) << 6;           // 64-row tile (bt>>2 in [0,192))
  const int kb = (bt & 3) * (KD / 4);      // K quarter
  const int fr = l & 15, fg = l >> 4;
  // A staging: slot=tid -> row sR (0..31), 16B chunk (sc ^ (sR&7)); slot+256 = +32 rows
  const int sR = tid >> 3;
  const int sc = (tid & 7) ^ (sR & 7);
  const float* aRun = adj + (size_t)(r0 + sR) * KD + kb + (sc << 2);
  // B staging (per-wave redundant, slot=l): col bc (0..15), 8k-group bh
  const int bc = l >> 2;
  const int bh = (l & 3) ^ (bc & 3);
  const unsigned short* bRun = h2T + (size_t)bc * KD + kb + (bh << 3);
  const unsigned char* aW = (const unsigned char*)&As[0][0] + (w << 10);
  const unsigned char* bW = (const unsigned char*)&Bs[0][0];   // same for all waves
  // frag lane offsets: A row R = w*16+fr (16B slots j^(R&7), j=2fg,2fg+1); B col fr
  const int R = (w << 4) + fr;
  const int aOff0 = R * 128 + ((((fg << 1) | 0) ^ (R & 7)) << 4);
  const int aOff1 = R * 128 + ((((fg << 1) | 1) ^ (R & 7)) << 4);
  const int bOff = fr * 64 + ((fg ^ (fr & 3)) << 4);
  f32x4 acc = {0.f, 0.f, 0.f, 0.f};
  const int NS = (KD / 4) / 32;  // 96
#pragma unroll
  for (int d = 0; d < 3; ++d) {
    gload16(aRun, (void*)(aW + d * 8192));
    gload16(aRun + (size_t)32 * KD, (void*)(aW + d * 8192 + 4096));
    gload16(bRun, (void*)(bW + d * 1024));
    aRun += 32; bRun += 32;
  }
#define L2_COMPUTE(S)                                                          \
  {                                                                            \
    const unsigned char* ab = (const unsigned char*)&As[(S) & 3][0];           \
    const unsigned char* bb = (const unsigned char*)&Bs[(S) & 3][0];           \
    bf16x8 a = cvt8(*(const float4*)(ab + aOff0), *(const float4*)(ab + aOff1)); \
    bf16x8 b = *(const bf16x8*)(bb + bOff);                                    \
    acc = mfma16(a, b, acc);                                                   \
  }
  for (int s = 0; s < NS - 3; ++s) {
    WAITV(6);
    BAR();
    int d = (s + 3) & 3;
    gload16(aRun, (void*)(aW + d * 8192));
    gload16(aRun + (size_t)32 * KD, (void*)(aW + d * 8192 + 4096));
    gload16(bRun, (void*)(bW + d * 1024));
    aRun += 32; bRun += 32;
    L2_COMPUTE(s);
  }
  WAITV(6); BAR(); L2_COMPUTE(NS - 3);
  WAITV(3); BAR(); L2_COMPUTE(NS - 2);
  WAITV(0); BAR(); L2_COMPUTE(NS - 1);
  float* op = out + (size_t)(r0 + (w << 4) + (fg << 2)) * NOUT + fr;
#pragma unroll
  for (int q = 0; q < 4; ++q) atomicAdd(op + q * NOUT, acc[q]);
}

extern "C" void kernel_launch(void* const* d_in, const int* in_sizes, int n_in,
                              void* d_out, int out_size, void* d_ws, size_t ws_size,
                              hipStream_t stream) {
  const float* x   = (const float*)d_in[0];
  const float* adj = (const float*)d_in[1];
  const float* W1  = (const float*)d_in[2];
  const float* b1  = (const float*)d_in[3];
  const float* W2  = (const float*)d_in[4];
  const float* b2  = (const float*)d_in[5];
  float* out = (float*)d_out;
  char* ws = (char*)d_ws;
  // ws layout (bytes): W1T 65536 | W2T 2048 | h1T 1572864 | H 1572864 | h2T 393216
  unsigned short* W1T = (unsigned short*)(ws);
  unsigned short* W2T = (unsigned short*)(ws + 65536);
  unsigned short* h1T = (unsigned short*)(ws + 67584);
  unsigned short* Hm  = (unsigned short*)(ws + 1640448);
  unsigned short* h2T = (unsigned short*)(ws + 3213312);

  hipLaunchKernelGGL(k_setup, dim3(900), dim3(256), 0, stream, W1, W2, W1T, W2T, out);
  hipLaunchKernelGGL(k_g1, dim3(KD / 16), dim3(256), 0, stream, x, W1T, b1, h1T);
  hipLaunchKernelGGL(k_l1, dim3(KD / 16), dim3(256), 0, stream, adj, h1T, Hm);
  hipLaunchKernelGGL(k_g2, dim3(KD / 16), dim3(64), 0, stream, Hm, W2T, b2, h2T);
  hipLaunchKernelGGL(k_l2, dim3((KD / 64) * 4), dim3(256), 0, stream, adj, h2T, out);
}